// Round 6
// baseline (234.868 us; speedup 1.0000x reference)
//
#include <hip/hip_runtime.h>
#include <hip/hip_bf16.h>
#include <math.h>

#define BATCH 2
#define SEQ   2048
#define HID   1024
#define NH    16
#define HD    64
#define MROWS (BATCH * SEQ)   // 4096
#define VSTR  4160            // padded row stride of V' (avoid 8192B channel camping)

typedef unsigned short u16;
typedef short bf16x8 __attribute__((ext_vector_type(8)));
typedef short bf16x4 __attribute__((ext_vector_type(4)));
typedef float f32x4  __attribute__((ext_vector_type(4)));

#define LOG2E 1.4426950408889634f
#define C2    (0.125f * LOG2E)      // score scale folded into log2 domain
#define M2F   23.083120f            // fixed softmax shift (shift-invariant)

static __device__ __forceinline__ u16 f2bf(float f) {
    union { float f; unsigned int u; } v; v.f = f;
    unsigned int r = (v.u + 0x7FFF + ((v.u >> 16) & 1)) >> 16;  // RNE
    return (u16)r;
}

static __device__ __forceinline__ unsigned int pk_bf16(float a, float b) {
    union { __hip_bfloat162 h; unsigned int u; } r;
    float2 f; f.x = a; f.y = b;
    r.h = __float22bfloat162_rn(f);
    return r.u;
}

static __device__ __forceinline__ f32x4 mfma16(bf16x8 a, bf16x8 b, f32x4 c) {
    return __builtin_amdgcn_mfma_f32_16x16x32_bf16(a, b, c, 0, 0, 0);
}

// K=16 MFMA for PV (P stays in registers).  Fallback: zero-pad to K=32 —
// equivalent since A and B occupy the same k-slots.
static __device__ __forceinline__ f32x4 mfma16k16(bf16x4 a, bf16x4 b, f32x4 c) {
#if __has_builtin(__builtin_amdgcn_mfma_f32_16x16x16bf16_1k)
    return __builtin_amdgcn_mfma_f32_16x16x16bf16_1k(a, b, c, 0, 0, 0);
#else
    bf16x8 a8 = {a[0], a[1], a[2], a[3], 0, 0, 0, 0};
    bf16x8 b8 = {b[0], b[1], b[2], b[3], 0, 0, 0, 0};
    return __builtin_amdgcn_mfma_f32_16x16x32_bf16(a8, b8, c, 0, 0, 0);
#endif
}

// global -> LDS async copy, 16 B per lane; LDS dest = wave-uniform base + lane*16.
static __device__ __forceinline__ void ldsload16(const void* g, void* l) {
    __builtin_amdgcn_global_load_lds(
        (const __attribute__((address_space(1))) void*)(unsigned long long)(uintptr_t)g,
        (__attribute__((address_space(3))) void*)(unsigned int)(uintptr_t)l,
        16, 0, 0);
}

// ---------------------------------------------------------------------------
// Fused prep: [0,4096) weight cast; [4096,8192) LayerNorm; [8192,8196) mask2.
// ---------------------------------------------------------------------------
__global__ __launch_bounds__(256) void prep_kernel(const float* __restrict__ x,
                                                   const float* __restrict__ gamma,
                                                   const float* __restrict__ beta,
                                                   u16* __restrict__ h,
                                                   const float* __restrict__ w0,
                                                   const float* __restrict__ w1,
                                                   const float* __restrict__ w2,
                                                   const float* __restrict__ w3,
                                                   u16* o0, u16* o1, u16* o2, u16* o3,
                                                   const float* __restrict__ maskg,
                                                   float* __restrict__ m2g)
{
    __shared__ float red[8];
    const int t = threadIdx.x;
    if (blockIdx.x >= 8192) {
        const int idx = ((blockIdx.x - 8192) * 256 + t) * 4;
        const float4 m = *(const float4*)(maskg + idx);
        float4 o;
        o.x = fmaf(-1000.0f * (1.0f - m.x), LOG2E, -M2F);
        o.y = fmaf(-1000.0f * (1.0f - m.y), LOG2E, -M2F);
        o.z = fmaf(-1000.0f * (1.0f - m.z), LOG2E, -M2F);
        o.w = fmaf(-1000.0f * (1.0f - m.w), LOG2E, -M2F);
        *(float4*)(m2g + idx) = o;
        return;
    }
    if (blockIdx.x < 4096) {
        const int blk = blockIdx.x;
        const int which = blk >> 10;
        const int lb = blk & 1023;
        const float* src = which == 0 ? w0 : which == 1 ? w1 : which == 2 ? w2 : w3;
        u16* dst = which == 0 ? o0 : which == 1 ? o1 : which == 2 ? o2 : o3;
        const int idx = (lb * 256 + t) * 4;
        const float4 f = *(const float4*)(src + idx);
        union { u16 s[4]; uint2 v; } p;
        p.s[0] = f2bf(f.x); p.s[1] = f2bf(f.y); p.s[2] = f2bf(f.z); p.s[3] = f2bf(f.w);
        *(uint2*)(dst + idx) = p.v;
        return;
    }
    const int row = blockIdx.x - 4096;
    const float4 xv = ((const float4*)(x + (size_t)row * HID))[t];
    float s  = xv.x + xv.y + xv.z + xv.w;
    float ss = xv.x * xv.x + xv.y * xv.y + xv.z * xv.z + xv.w * xv.w;
#pragma unroll
    for (int off = 32; off > 0; off >>= 1) {
        s  += __shfl_down(s, off);
        ss += __shfl_down(ss, off);
    }
    const int wid = t >> 6;
    if ((t & 63) == 0) { red[wid] = s; red[4 + wid] = ss; }
    __syncthreads();
    s  = red[0] + red[1] + red[2] + red[3];
    ss = red[4] + red[5] + red[6] + red[7];
    const float mu   = s * (1.0f / HID);
    const float var  = ss * (1.0f / HID) - mu * mu;
    const float rstd = rsqrtf(var + 1e-12f);
    const float4 g  = ((const float4*)gamma)[t];
    const float4 bb = ((const float4*)beta)[t];
    union { u16 s[4]; uint2 v; } p;
    p.s[0] = f2bf((xv.x - mu) * rstd * g.x + bb.x);
    p.s[1] = f2bf((xv.y - mu) * rstd * g.y + bb.y);
    p.s[2] = f2bf((xv.z - mu) * rstd * g.z + bb.z);
    p.s[3] = f2bf((xv.w - mu) * rstd * g.w + bb.w);
    ((uint2*)(h + (size_t)row * HID))[t] = p.v;
}

// ---------------------------------------------------------------------------
// MFMA GEMM core, double-buffered (unchanged from round 5).
// ---------------------------------------------------------------------------
static __device__ __forceinline__ void gemm_core(const u16* __restrict__ A,
                                                 const u16* __restrict__ B,
                                                 int K, int bm, int bn,
                                                 u16* As, u16* Bs,
                                                 int wave, int lane,
                                                 f32x4 acc[4][4])
{
    const int l15  = lane & 15;
    const int quad = lane >> 4;
    const int wm = (wave >> 1) * 64;
    const int wn = (wave & 1) * 64;

    const int c1 = wave * 64 + lane;
    const int c2 = c1 + 256;
    const u16* A1 = A + (size_t)(bm + (c1 >> 2)) * K + (c1 & 3) * 8;
    const u16* A2 = A + (size_t)(bm + (c2 >> 2)) * K + (c2 & 3) * 8;
    const u16* B1 = B + (size_t)(bn + (c1 >> 2)) * K + (c1 & 3) * 8;
    const u16* B2 = B + (size_t)(bn + (c2 >> 2)) * K + (c2 & 3) * 8;
    const int o1 = wave * 512;
    const int o2 = 2048 + wave * 512;

    ldsload16(A1, As + o1);
    ldsload16(A2, As + o2);
    ldsload16(B1, Bs + o1);
    ldsload16(B2, Bs + o2);

    const int nstep = K >> 5;
    for (int i = 0; i < nstep; i++) {
        __syncthreads();
        const int cb = (i & 1) * 4096;
        if (i + 1 < nstep) {
            const int nb = ((i + 1) & 1) * 4096;
            const int k0 = (i + 1) * 32;
            ldsload16(A1 + k0, As + nb + o1);
            ldsload16(A2 + k0, As + nb + o2);
            ldsload16(B1 + k0, Bs + nb + o1);
            ldsload16(B2 + k0, Bs + nb + o2);
        }
        bf16x8 af[4], bfr[4];
#pragma unroll
        for (int mt = 0; mt < 4; mt++)
            af[mt] = *(const bf16x8*)&As[cb + (wm + mt * 16 + l15) * 32 + quad * 8];
#pragma unroll
        for (int nt = 0; nt < 4; nt++)
            bfr[nt] = *(const bf16x8*)&Bs[cb + (wn + nt * 16 + l15) * 32 + quad * 8];
#pragma unroll
        for (int mt = 0; mt < 4; mt++)
#pragma unroll
            for (int nt = 0; nt < 4; nt++)
                acc[mt][nt] = mfma16(af[mt], bfr[nt], acc[mt][nt]);
    }
}

// ---------------------------------------------------------------------------
// Fused QKV (unchanged from round 5).
// ---------------------------------------------------------------------------
__global__ __launch_bounds__(256) void qkv_gemm(const u16* __restrict__ h,
                                                const u16* __restrict__ wq,
                                                const u16* __restrict__ wk,
                                                const u16* __restrict__ wv,
                                                const float* __restrict__ bq,
                                                const float* __restrict__ bk,
                                                const float* __restrict__ bv,
                                                u16* __restrict__ qo,
                                                u16* __restrict__ ko,
                                                u16* __restrict__ vo)
{
    __shared__ u16 As[8192];
    __shared__ u16 Bs[8192];
    const int blk  = blockIdx.x;
    const int wave = threadIdx.x >> 6;
    const int lane = threadIdx.x & 63;
    const int l15  = lane & 15;
    const int quad = lane >> 4;
    const int wm = (wave >> 1) * 64;
    const int wn = (wave & 1) * 64;

    f32x4 acc[4][4];
#pragma unroll
    for (int mt = 0; mt < 4; mt++)
#pragma unroll
        for (int nt = 0; nt < 4; nt++) acc[mt][nt] = (f32x4)0.0f;

    if (blk < 512) {
        const u16* W     = (blk < 256) ? wq : wk;
        const float* bia = (blk < 256) ? bq : bk;
        u16* out         = (blk < 256) ? qo : ko;
        const int local = blk & 255;
        const int bm = (local >> 3) * 128;
        const int bn = (local & 7) * 128;
        gemm_core(h, W, HID, bm, bn, As, Bs, wave, lane, acc);

        float bv4[4];
#pragma unroll
        for (int nt = 0; nt < 4; nt++) bv4[nt] = bia[bn + wn + nt * 16 + l15];
#pragma unroll
        for (int mt = 0; mt < 4; mt++)
#pragma unroll
            for (int r = 0; r < 4; r++) {
                const int m  = bm + wm + mt * 16 + quad * 4 + r;
                const int bI = m >> 11;
                const int sI = m & (SEQ - 1);
#pragma unroll
                for (int nt = 0; nt < 4; nt++) {
                    const int n  = bn + wn + nt * 16 + l15;
                    const int hh = n >> 6;
                    const int d  = n & 63;
                    out[(((size_t)(bI * NH + hh) * SEQ + sI) << 6) + d] =
                        f2bf(acc[mt][nt][r] + bv4[nt]);
                }
            }
    } else {
        const int local = blk - 512;
        const int bm = (local & 7) * 128;
        const int bn = (local >> 3) * 128;
        gemm_core(wv, h, HID, bm, bn, As, Bs, wave, lane, acc);

#pragma unroll
        for (int mt = 0; mt < 4; mt++) {
            const f32x4 bm4 = *(const f32x4*)&bv[bm + wm + mt * 16 + quad * 4];
#pragma unroll
            for (int r = 0; r < 4; r++) {
                const int row = bm + wm + mt * 16 + quad * 4 + r;
#pragma unroll
                for (int nt = 0; nt < 4; nt++) {
                    const int col = bn + wn + nt * 16 + l15;
                    vo[(size_t)row * VSTR + col] = f2bf(acc[mt][nt][r] + bm4[r]);
                }
            }
        }
    }
}

// ---------------------------------------------------------------------------
// Output projection (unchanged from round 5).
// ---------------------------------------------------------------------------
__global__ __launch_bounds__(256) void out_gemm(const u16* __restrict__ ctx,
                                                const u16* __restrict__ wd,
                                                const float* __restrict__ bd,
                                                float* __restrict__ out)
{
    __shared__ u16 As[8192];
    __shared__ u16 Bs[8192];
    const int blk  = blockIdx.x;
    const int wave = threadIdx.x >> 6;
    const int lane = threadIdx.x & 63;
    const int l15  = lane & 15;
    const int quad = lane >> 4;
    const int wm = (wave >> 1) * 64;
    const int wn = (wave & 1) * 64;
    const int bm = (blk >> 3) * 128;
    const int bn = (blk & 7) * 128;

    f32x4 acc[4][4];
#pragma unroll
    for (int mt = 0; mt < 4; mt++)
#pragma unroll
        for (int nt = 0; nt < 4; nt++) acc[mt][nt] = (f32x4)0.0f;

    gemm_core(ctx, wd, HID, bm, bn, As, Bs, wave, lane, acc);

    float bv4[4];
#pragma unroll
    for (int nt = 0; nt < 4; nt++) bv4[nt] = bd[bn + wn + nt * 16 + l15];
#pragma unroll
    for (int mt = 0; mt < 4; mt++)
#pragma unroll
        for (int r = 0; r < 4; r++) {
            const int m = bm + wm + mt * 16 + quad * 4 + r;
#pragma unroll
            for (int nt = 0; nt < 4; nt++) {
                const int n = bn + wn + nt * 16 + l15;
                out[(size_t)m * HID + n] = acc[mt][nt][r] + bv4[nt];
            }
        }
}

// ---------------------------------------------------------------------------
// MFMA flash attention v4: split-KV across waves, barrier-free main loop.
// Block = 64 q x one (b,h); wave w handles kv tiles [w*512, w*512+512) for
// ALL 64 q.  Per-wave-private LDS staging (16 KB), explicit waitcnt ordering.
// P stays in registers: S^T C-layout == B-operand layout of K=16 MFMA.
// Epilogue: cross-wave O/l reduction (fixed-M partials are additive).
// ---------------------------------------------------------------------------
__global__ __launch_bounds__(256) void attn_mfma(const u16* __restrict__ qb,
                                                 const u16* __restrict__ kb,
                                                 const u16* __restrict__ vtb,
                                                 const float* __restrict__ m2g,
                                                 u16* __restrict__ ctx)
{
    // [0,65536): 4 waves x (K tile 8KB + V tile 8KB); reused by epilogue as
    // Opart[wave][16 k][64 lane] f32x4 and (after barrier 2) Ot[64][68] f32.
    // [65536,66560): ls[4 waves][64 q] f32.
    __shared__ __align__(16) char smem[66560];

    const int t    = threadIdx.x;
    const int wave = t >> 6;
    const int lane = t & 63;
    const int l15  = lane & 15;
    const int quad = lane >> 4;

    const int bh = blockIdx.x & 31;       // XCD swizzle: bh fastest
    const int qt = blockIdx.x >> 5;
    const int b  = bh >> 4;
    const int hh = bh & 15;
    const int q0 = qt * 64;

    const size_t headoff = (size_t)(b * NH + hh) * SEQ * HD;
    const u16* kbase = kb + headoff;
    const u16* vbase = vtb + (size_t)(hh * HD) * VSTR + b * SEQ;
    const float* m2b = m2g + b * SEQ;

    char* Ksw  = smem + wave * 16384;
    char* Vtsw = Ksw + 8192;

    // Q fragments for all 4 q-subtiles (B-operand, K=32 MFMA)
    bf16x8 Qf[4][2];
#pragma unroll
    for (int nt = 0; nt < 4; nt++)
#pragma unroll
        for (int ks2 = 0; ks2 < 2; ks2++)
            Qf[nt][ks2] = *(const bf16x8*)(qb + headoff +
                (size_t)(q0 + nt * 16 + l15) * HD + ks2 * 32 + quad * 8);

    f32x4 O[4][4];
#pragma unroll
    for (int mt = 0; mt < 4; mt++)
#pragma unroll
        for (int nt = 0; nt < 4; nt++) O[mt][nt] = (f32x4)0.0f;
    float ls4[4] = {0.0f, 0.0f, 0.0f, 0.0f};

    const int srow = lane >> 3;
    const int lcol = (lane & 7) ^ srow;                 // XOR-swizzled staging chunk
    const int swk0 = ((quad)     ^ (l15 & 7)) * 8;      // K frag chunk (u16 units)
    const int swk1 = ((quad + 4) ^ (l15 & 7)) * 8;
    const int cbase = wave * 512;                       // this wave's kv range

    // stage tile 0 (wave-private)
#pragma unroll
    for (int g = 0; g < 8; g++) {
        ldsload16(kbase + (size_t)(cbase + g * 8 + srow) * HD + lcol * 8, Ksw + g * 1024);
        ldsload16(vbase + (size_t)(g * 8 + srow) * VSTR + cbase + lcol * 8, Vtsw + g * 1024);
    }

    for (int j = 0; j < 8; j++) {
        const int c0 = cbase + j * 64;
        asm volatile("s_waitcnt vmcnt(0)" ::: "memory");   // tile j staged

        // pull ALL fragments of tile j into registers
        bf16x8 Ka[4][2];
#pragma unroll
        for (int ks = 0; ks < 4; ks++) {
            const u16* Kp = (const u16*)Ksw + (ks * 16 + l15) * 64;
            Ka[ks][0] = *(const bf16x8*)(Kp + swk0);
            Ka[ks][1] = *(const bf16x8*)(Kp + swk1);
        }
        bf16x4 Va[4][4];
#pragma unroll
        for (int mt2 = 0; mt2 < 4; mt2++) {
            const u16* Vp = (const u16*)Vtsw + (mt2 * 16 + l15) * 64 + ((quad & 1) << 2);
#pragma unroll
            for (int ks = 0; ks < 4; ks++)
                Va[mt2][ks] = *(const bf16x4*)(Vp +
                    ((((ks << 1) | (quad >> 1)) ^ (l15 & 7)) << 3));
        }
        asm volatile("s_waitcnt lgkmcnt(0)" ::: "memory");  // frags in regs

        // stage tile j+1 — flies during the compute below
        if (j + 1 < 8) {
            const int cn = c0 + 64;
#pragma unroll
            for (int g = 0; g < 8; g++) {
                ldsload16(kbase + (size_t)(cn + g * 8 + srow) * HD + lcol * 8, Ksw + g * 1024);
                ldsload16(vbase + (size_t)(g * 8 + srow) * VSTR + cn + lcol * 8, Vtsw + g * 1024);
            }
        }

        // per 16-kv chunk: S^T -> softmax -> packed P (registers only)
        bf16x4 Pk[4][4];
#pragma unroll
        for (int ks = 0; ks < 4; ks++) {
            f32x4 St[4];
#pragma unroll
            for (int nt = 0; nt < 4; nt++) {
                f32x4 a = (f32x4)0.0f;
                a = mfma16(Ka[ks][0], Qf[nt][0], a);
                a = mfma16(Ka[ks][1], Qf[nt][1], a);
                St[nt] = a;
            }
            const f32x4 mv = *(const f32x4*)(m2b + c0 + ks * 16 + quad * 4);
#pragma unroll
            for (int nt = 0; nt < 4; nt++) {
                const float p0 = __builtin_amdgcn_exp2f(fmaf(St[nt][0], C2, mv[0]));
                const float p1 = __builtin_amdgcn_exp2f(fmaf(St[nt][1], C2, mv[1]));
                const float p2 = __builtin_amdgcn_exp2f(fmaf(St[nt][2], C2, mv[2]));
                const float p3 = __builtin_amdgcn_exp2f(fmaf(St[nt][3], C2, mv[3]));
                ls4[nt] += (p0 + p1) + (p2 + p3);
                union { unsigned int u[2]; bf16x4 v; } pk;
                pk.u[0] = pk_bf16(p0, p1);
                pk.u[1] = pk_bf16(p2, p3);
                Pk[ks][nt] = pk.v;
            }
        }

        // O^T[d][q] += V^T-frag * P-frag  (K=16 MFMA, kv chunks = ks)
#pragma unroll
        for (int mt2 = 0; mt2 < 4; mt2++)
#pragma unroll
            for (int nt = 0; nt < 4; nt++) {
                f32x4 acc = O[mt2][nt];
#pragma unroll
                for (int ks = 0; ks < 4; ks++)
                    acc = mfma16k16(Va[mt2][ks], Pk[ks][nt], acc);
                O[mt2][nt] = acc;
            }
    }

    // lsum over quads (q column = nt*16 + l15 lives in lanes {l15, +16, +32, +48})
#pragma unroll
    for (int nt = 0; nt < 4; nt++) {
        ls4[nt] += __shfl_xor(ls4[nt], 16);
        ls4[nt] += __shfl_xor(ls4[nt], 32);
    }

    // write partials: Opart[wave][k=mt2*4+nt][lane] (f32x4), ls[wave][q]
    {
        float* Opart = (float*)(smem + wave * 16384);
#pragma unroll
        for (int mt2 = 0; mt2 < 4; mt2++)
#pragma unroll
            for (int nt = 0; nt < 4; nt++)
                *(f32x4*)(Opart + ((mt2 * 4 + nt) * 64 + lane) * 4) = O[mt2][nt];
        float* lsb = (float*)(smem + 65536);
        if (lane < 16) {
#pragma unroll
            for (int nt = 0; nt < 4; nt++)
                lsb[wave * 64 + nt * 16 + lane] = ls4[nt];
        }
    }
    __syncthreads();

    // cross-wave reduce: wave w owns d-tile mt2 = w
    f32x4 Of[4];
    {
        const float* lsb = (const float*)(smem + 65536);
#pragma unroll
        for (int nt = 0; nt < 4; nt++) {
            const int k = wave * 4 + nt;
            f32x4 s = *(const f32x4*)(smem + 0 * 16384 + (k * 64 + lane) * 16);
            s = s + *(const f32x4*)(smem + 1 * 16384 + (k * 64 + lane) * 16);
            s = s + *(const f32x4*)(smem + 2 * 16384 + (k * 64 + lane) * 16);
            s = s + *(const f32x4*)(smem + 3 * 16384 + (k * 64 + lane) * 16);
            const int q = nt * 16 + l15;
            const float lt = lsb[q] + lsb[64 + q] + lsb[128 + q] + lsb[192 + q];
            Of[nt] = s * (1.0f / lt);
        }
    }
    __syncthreads();

    // transpose via LDS: Ot[q][d], d = wave*16 + quad*4 + r
    {
        float* Ot = (float*)smem;
#pragma unroll
        for (int nt = 0; nt < 4; nt++)
            *(f32x4*)(Ot + (nt * 16 + l15) * 68 + wave * 16 + quad * 4) = Of[nt];
    }
    __syncthreads();

    // coalesced bf16 store of the block's 64x64 ctx tile
    {
        const float* Ot = (const float*)smem;
        const int ql  = t >> 2;
        const int seg = t & 3;
        const float* srcp = Ot + ql * 68 + seg * 16;
        u16* dstp = ctx + (size_t)(b * SEQ + q0 + ql) * HID + hh * 64 + seg * 16;
#pragma unroll
        for (int jj = 0; jj < 2; jj++) {
            union { u16 s[8]; uint4 v; } p;
#pragma unroll
            for (int i = 0; i < 8; i++) p.s[i] = f2bf(srcp[jj * 8 + i]);
            *(uint4*)(dstp + jj * 8) = p.v;
        }
    }
}

// ---------------------------------------------------------------------------
extern "C" void kernel_launch(void* const* d_in, const int* in_sizes, int n_in,
                              void* d_out, int out_size, void* d_ws, size_t ws_size,
                              hipStream_t stream)
{
    const float* hs    = (const float*)d_in[0];
    const float* mask  = (const float*)d_in[1];
    const float* Wq    = (const float*)d_in[2];
    const float* bq    = (const float*)d_in[3];
    const float* Wk    = (const float*)d_in[4];
    const float* bk    = (const float*)d_in[5];
    const float* Wv    = (const float*)d_in[6];
    const float* bv    = (const float*)d_in[7];
    const float* Wd    = (const float*)d_in[8];
    const float* bd    = (const float*)d_in[9];
    const float* gamma = (const float*)d_in[10];
    const float* beta  = (const float*)d_in[11];
    float* out = (float*)d_out;

    const size_t NE = (size_t)MROWS * HID;
    u16* ws   = (u16*)d_ws;
    u16* h    = ws;                          // bf16 [MROWS][HID]
    u16* qbb  = ws + NE;                     // bf16 [B,NH,S,HD]
    u16* kbb  = qbb + NE;                    // bf16 [B,NH,S,HD]
    u16* vtb  = kbb + NE;                    // bf16 [HID][VSTR]
    u16* ctxb = vtb + (size_t)HID * VSTR;    // bf16 [MROWS][HID]
    u16* wqb  = ctxb + NE;
    u16* wkb  = wqb + HID * HID;
    u16* wvb  = wkb + HID * HID;
    u16* wdb  = wvb + HID * HID;
    float* m2 = (float*)(wdb + HID * HID);   // fp32 [MROWS] precomputed mask2

    prep_kernel<<<8196, 256, 0, stream>>>(hs, gamma, beta, h,
                                          Wq, Wk, Wv, Wd, wqb, wkb, wvb, wdb,
                                          mask, m2);

    qkv_gemm<<<768, 256, 0, stream>>>(h, wqb, wkb, wvb, bq, bk, bv, qbb, kbb, vtb);

    attn_mfma<<<1024, 256, 0, stream>>>(qbb, kbb, vtb, m2, ctxb);

    out_gemm<<<256, 256, 0, stream>>>(ctxb, wdb, bd, out);
}

// Round 7
// 223.942 us; speedup vs baseline: 1.0488x; 1.0488x over previous
//
#include <hip/hip_runtime.h>
#include <hip/hip_bf16.h>
#include <math.h>

#define BATCH 2
#define SEQ   2048
#define HID   1024
#define NH    16
#define HD    64
#define MROWS (BATCH * SEQ)   // 4096
#define VSTR  4160            // padded row stride of V' (avoid 8192B channel camping)

typedef unsigned short u16;
typedef short bf16x8 __attribute__((ext_vector_type(8)));
typedef short bf16x4 __attribute__((ext_vector_type(4)));
typedef float f32x4  __attribute__((ext_vector_type(4)));

#define LOG2E 1.4426950408889634f
#define C2    (0.125f * LOG2E)      // score scale folded into log2 domain
#define M2F   23.083120f            // fixed softmax shift (shift-invariant)

static __device__ __forceinline__ u16 f2bf(float f) {
    union { float f; unsigned int u; } v; v.f = f;
    unsigned int r = (v.u + 0x7FFF + ((v.u >> 16) & 1)) >> 16;  // RNE
    return (u16)r;
}

static __device__ __forceinline__ unsigned int pk_bf16(float a, float b) {
    union { __hip_bfloat162 h; unsigned int u; } r;
    float2 f; f.x = a; f.y = b;
    r.h = __float22bfloat162_rn(f);
    return r.u;
}

static __device__ __forceinline__ f32x4 mfma16(bf16x8 a, bf16x8 b, f32x4 c) {
    return __builtin_amdgcn_mfma_f32_16x16x32_bf16(a, b, c, 0, 0, 0);
}

// K=16 MFMA for PV (P stays in registers).  Fallback zero-pads to K=32.
static __device__ __forceinline__ f32x4 mfma16k16(bf16x4 a, bf16x4 b, f32x4 c) {
#if __has_builtin(__builtin_amdgcn_mfma_f32_16x16x16bf16_1k)
    return __builtin_amdgcn_mfma_f32_16x16x16bf16_1k(a, b, c, 0, 0, 0);
#else
    bf16x8 a8 = {a[0], a[1], a[2], a[3], 0, 0, 0, 0};
    bf16x8 b8 = {b[0], b[1], b[2], b[3], 0, 0, 0, 0};
    return __builtin_amdgcn_mfma_f32_16x16x32_bf16(a8, b8, c, 0, 0, 0);
#endif
}

// global -> LDS async copy, 16 B per lane; LDS dest = wave-uniform base + lane*16.
static __device__ __forceinline__ void ldsload16(const void* g, void* l) {
    __builtin_amdgcn_global_load_lds(
        (const __attribute__((address_space(1))) void*)(unsigned long long)(uintptr_t)g,
        (__attribute__((address_space(3))) void*)(unsigned int)(uintptr_t)l,
        16, 0, 0);
}

// ---------------------------------------------------------------------------
// Fused prep: [0,4096) weight cast; [4096,8192) LayerNorm; [8192,8196) mask2.
// ---------------------------------------------------------------------------
__global__ __launch_bounds__(256) void prep_kernel(const float* __restrict__ x,
                                                   const float* __restrict__ gamma,
                                                   const float* __restrict__ beta,
                                                   u16* __restrict__ h,
                                                   const float* __restrict__ w0,
                                                   const float* __restrict__ w1,
                                                   const float* __restrict__ w2,
                                                   const float* __restrict__ w3,
                                                   u16* o0, u16* o1, u16* o2, u16* o3,
                                                   const float* __restrict__ maskg,
                                                   float* __restrict__ m2g)
{
    __shared__ float red[8];
    const int t = threadIdx.x;
    if (blockIdx.x >= 8192) {
        const int idx = ((blockIdx.x - 8192) * 256 + t) * 4;
        const float4 m = *(const float4*)(maskg + idx);
        float4 o;
        o.x = fmaf(-1000.0f * (1.0f - m.x), LOG2E, -M2F);
        o.y = fmaf(-1000.0f * (1.0f - m.y), LOG2E, -M2F);
        o.z = fmaf(-1000.0f * (1.0f - m.z), LOG2E, -M2F);
        o.w = fmaf(-1000.0f * (1.0f - m.w), LOG2E, -M2F);
        *(float4*)(m2g + idx) = o;
        return;
    }
    if (blockIdx.x < 4096) {
        const int blk = blockIdx.x;
        const int which = blk >> 10;
        const int lb = blk & 1023;
        const float* src = which == 0 ? w0 : which == 1 ? w1 : which == 2 ? w2 : w3;
        u16* dst = which == 0 ? o0 : which == 1 ? o1 : which == 2 ? o2 : o3;
        const int idx = (lb * 256 + t) * 4;
        const float4 f = *(const float4*)(src + idx);
        union { u16 s[4]; uint2 v; } p;
        p.s[0] = f2bf(f.x); p.s[1] = f2bf(f.y); p.s[2] = f2bf(f.z); p.s[3] = f2bf(f.w);
        *(uint2*)(dst + idx) = p.v;
        return;
    }
    const int row = blockIdx.x - 4096;
    const float4 xv = ((const float4*)(x + (size_t)row * HID))[t];
    float s  = xv.x + xv.y + xv.z + xv.w;
    float ss = xv.x * xv.x + xv.y * xv.y + xv.z * xv.z + xv.w * xv.w;
#pragma unroll
    for (int off = 32; off > 0; off >>= 1) {
        s  += __shfl_down(s, off);
        ss += __shfl_down(ss, off);
    }
    const int wid = t >> 6;
    if ((t & 63) == 0) { red[wid] = s; red[4 + wid] = ss; }
    __syncthreads();
    s  = red[0] + red[1] + red[2] + red[3];
    ss = red[4] + red[5] + red[6] + red[7];
    const float mu   = s * (1.0f / HID);
    const float var  = ss * (1.0f / HID) - mu * mu;
    const float rstd = rsqrtf(var + 1e-12f);
    const float4 g  = ((const float4*)gamma)[t];
    const float4 bb = ((const float4*)beta)[t];
    union { u16 s[4]; uint2 v; } p;
    p.s[0] = f2bf((xv.x - mu) * rstd * g.x + bb.x);
    p.s[1] = f2bf((xv.y - mu) * rstd * g.y + bb.y);
    p.s[2] = f2bf((xv.z - mu) * rstd * g.z + bb.z);
    p.s[3] = f2bf((xv.w - mu) * rstd * g.w + bb.w);
    ((uint2*)(h + (size_t)row * HID))[t] = p.v;
}

// ---------------------------------------------------------------------------
// MFMA GEMM core, double-buffered (unchanged).
// ---------------------------------------------------------------------------
static __device__ __forceinline__ void gemm_core(const u16* __restrict__ A,
                                                 const u16* __restrict__ B,
                                                 int K, int bm, int bn,
                                                 u16* As, u16* Bs,
                                                 int wave, int lane,
                                                 f32x4 acc[4][4])
{
    const int l15  = lane & 15;
    const int quad = lane >> 4;
    const int wm = (wave >> 1) * 64;
    const int wn = (wave & 1) * 64;

    const int c1 = wave * 64 + lane;
    const int c2 = c1 + 256;
    const u16* A1 = A + (size_t)(bm + (c1 >> 2)) * K + (c1 & 3) * 8;
    const u16* A2 = A + (size_t)(bm + (c2 >> 2)) * K + (c2 & 3) * 8;
    const u16* B1 = B + (size_t)(bn + (c1 >> 2)) * K + (c1 & 3) * 8;
    const u16* B2 = B + (size_t)(bn + (c2 >> 2)) * K + (c2 & 3) * 8;
    const int o1 = wave * 512;
    const int o2 = 2048 + wave * 512;

    ldsload16(A1, As + o1);
    ldsload16(A2, As + o2);
    ldsload16(B1, Bs + o1);
    ldsload16(B2, Bs + o2);

    const int nstep = K >> 5;
    for (int i = 0; i < nstep; i++) {
        __syncthreads();
        const int cb = (i & 1) * 4096;
        if (i + 1 < nstep) {
            const int nb = ((i + 1) & 1) * 4096;
            const int k0 = (i + 1) * 32;
            ldsload16(A1 + k0, As + nb + o1);
            ldsload16(A2 + k0, As + nb + o2);
            ldsload16(B1 + k0, Bs + nb + o1);
            ldsload16(B2 + k0, Bs + nb + o2);
        }
        bf16x8 af[4], bfr[4];
#pragma unroll
        for (int mt = 0; mt < 4; mt++)
            af[mt] = *(const bf16x8*)&As[cb + (wm + mt * 16 + l15) * 32 + quad * 8];
#pragma unroll
        for (int nt = 0; nt < 4; nt++)
            bfr[nt] = *(const bf16x8*)&Bs[cb + (wn + nt * 16 + l15) * 32 + quad * 8];
#pragma unroll
        for (int mt = 0; mt < 4; mt++)
#pragma unroll
            for (int nt = 0; nt < 4; nt++)
                acc[mt][nt] = mfma16(af[mt], bfr[nt], acc[mt][nt]);
    }
}

// ---------------------------------------------------------------------------
// Fused QKV (unchanged).
// ---------------------------------------------------------------------------
__global__ __launch_bounds__(256) void qkv_gemm(const u16* __restrict__ h,
                                                const u16* __restrict__ wq,
                                                const u16* __restrict__ wk,
                                                const u16* __restrict__ wv,
                                                const float* __restrict__ bq,
                                                const float* __restrict__ bk,
                                                const float* __restrict__ bv,
                                                u16* __restrict__ qo,
                                                u16* __restrict__ ko,
                                                u16* __restrict__ vo)
{
    __shared__ u16 As[8192];
    __shared__ u16 Bs[8192];
    const int blk  = blockIdx.x;
    const int wave = threadIdx.x >> 6;
    const int lane = threadIdx.x & 63;
    const int l15  = lane & 15;
    const int quad = lane >> 4;
    const int wm = (wave >> 1) * 64;
    const int wn = (wave & 1) * 64;

    f32x4 acc[4][4];
#pragma unroll
    for (int mt = 0; mt < 4; mt++)
#pragma unroll
        for (int nt = 0; nt < 4; nt++) acc[mt][nt] = (f32x4)0.0f;

    if (blk < 512) {
        const u16* W     = (blk < 256) ? wq : wk;
        const float* bia = (blk < 256) ? bq : bk;
        u16* out         = (blk < 256) ? qo : ko;
        const int local = blk & 255;
        const int bm = (local >> 3) * 128;
        const int bn = (local & 7) * 128;
        gemm_core(h, W, HID, bm, bn, As, Bs, wave, lane, acc);

        float bv4[4];
#pragma unroll
        for (int nt = 0; nt < 4; nt++) bv4[nt] = bia[bn + wn + nt * 16 + l15];
#pragma unroll
        for (int mt = 0; mt < 4; mt++)
#pragma unroll
            for (int r = 0; r < 4; r++) {
                const int m  = bm + wm + mt * 16 + quad * 4 + r;
                const int bI = m >> 11;
                const int sI = m & (SEQ - 1);
#pragma unroll
                for (int nt = 0; nt < 4; nt++) {
                    const int n  = bn + wn + nt * 16 + l15;
                    const int hh = n >> 6;
                    const int d  = n & 63;
                    out[(((size_t)(bI * NH + hh) * SEQ + sI) << 6) + d] =
                        f2bf(acc[mt][nt][r] + bv4[nt]);
                }
            }
    } else {
        const int local = blk - 512;
        const int bm = (local & 7) * 128;
        const int bn = (local >> 3) * 128;
        gemm_core(wv, h, HID, bm, bn, As, Bs, wave, lane, acc);

#pragma unroll
        for (int mt = 0; mt < 4; mt++) {
            const f32x4 bm4 = *(const f32x4*)&bv[bm + wm + mt * 16 + quad * 4];
#pragma unroll
            for (int r = 0; r < 4; r++) {
                const int row = bm + wm + mt * 16 + quad * 4 + r;
#pragma unroll
                for (int nt = 0; nt < 4; nt++) {
                    const int col = bn + wn + nt * 16 + l15;
                    vo[(size_t)row * VSTR + col] = f2bf(acc[mt][nt][r] + bm4[r]);
                }
            }
        }
    }
}

// ---------------------------------------------------------------------------
// Output projection (unchanged).
// ---------------------------------------------------------------------------
__global__ __launch_bounds__(256) void out_gemm(const u16* __restrict__ ctx,
                                                const u16* __restrict__ wd,
                                                const float* __restrict__ bd,
                                                float* __restrict__ out)
{
    __shared__ u16 As[8192];
    __shared__ u16 Bs[8192];
    const int blk  = blockIdx.x;
    const int wave = threadIdx.x >> 6;
    const int lane = threadIdx.x & 63;
    const int l15  = lane & 15;
    const int quad = lane >> 4;
    const int wm = (wave >> 1) * 64;
    const int wn = (wave & 1) * 64;
    const int bm = (blk >> 3) * 128;
    const int bn = (blk & 7) * 128;

    f32x4 acc[4][4];
#pragma unroll
    for (int mt = 0; mt < 4; mt++)
#pragma unroll
        for (int nt = 0; nt < 4; nt++) acc[mt][nt] = (f32x4)0.0f;

    gemm_core(ctx, wd, HID, bm, bn, As, Bs, wave, lane, acc);

    float bv4[4];
#pragma unroll
    for (int nt = 0; nt < 4; nt++) bv4[nt] = bd[bn + wn + nt * 16 + l15];
#pragma unroll
    for (int mt = 0; mt < 4; mt++)
#pragma unroll
        for (int r = 0; r < 4; r++) {
            const int m = bm + wm + mt * 16 + quad * 4 + r;
#pragma unroll
            for (int nt = 0; nt < 4; nt++) {
                const int n = bn + wn + nt * 16 + l15;
                out[(size_t)m * HID + n] = acc[mt][nt][r] + bv4[nt];
            }
        }
}

// ---------------------------------------------------------------------------
// MFMA flash attention v5: block = 128 q, 4 waves, wave = 32 q (2 nt tiles).
// Shared double-buffered K/V tiles (64 kv, XOR-swizzled, global_load_lds),
// single barrier per tile with prefetch-after-barrier.  P stays in registers
// (S^T C-layout == B-operand of K=16 MFMA).  Fixed-M exp2 softmax.
// ---------------------------------------------------------------------------
__global__ __launch_bounds__(256) void attn_mfma(const u16* __restrict__ qb,
                                                 const u16* __restrict__ kb,
                                                 const u16* __restrict__ vtb,
                                                 const float* __restrict__ m2g,
                                                 u16* __restrict__ ctx)
{
    // K bufs @0,8192 | V bufs @16384,24576; epilogue reuses all of it as
    // 4 waves x float[32][68] (34816 B).
    __shared__ __align__(16) char smem[34816];

    const int t    = threadIdx.x;
    const int wave = t >> 6;
    const int lane = t & 63;
    const int l15  = lane & 15;
    const int quad = lane >> 4;

    const int bh = blockIdx.x & 31;       // XCD swizzle: bh fastest
    const int qt = blockIdx.x >> 5;
    const int b  = bh >> 4;
    const int hh = bh & 15;
    const int q0 = qt * 128;

    const size_t headoff = (size_t)(b * NH + hh) * SEQ * HD;
    const u16* kbase = kb + headoff;
    const u16* vbase = vtb + (size_t)(hh * HD) * VSTR + b * SEQ;
    const float* m2b = m2g + b * SEQ;

    // Q fragments: wave owns q in [q0+wave*32, +32) as nt=0,1 tiles
    bf16x8 Qf[2][2];
#pragma unroll
    for (int nt = 0; nt < 2; nt++)
#pragma unroll
        for (int ks2 = 0; ks2 < 2; ks2++)
            Qf[nt][ks2] = *(const bf16x8*)(qb + headoff +
                (size_t)(q0 + wave * 32 + nt * 16 + l15) * HD + ks2 * 32 + quad * 8);

    f32x4 O[4][2];
#pragma unroll
    for (int mt2 = 0; mt2 < 4; mt2++)
#pragma unroll
        for (int nt = 0; nt < 2; nt++) O[mt2][nt] = (f32x4)0.0f;
    float ls2[2] = {0.0f, 0.0f};

    const int srow = lane >> 3;
    const int lcol = (lane & 7) ^ srow;                 // XOR-swizzled staging chunk
    const int swk0 = ((quad)     ^ (l15 & 7)) * 8;      // K frag chunks (u16 units)
    const int swk1 = ((quad + 4) ^ (l15 & 7)) * 8;
    const int g0 = wave * 2;                            // staging groups {g0, g0+1}

    // stage tile 0 into buffer 0 (cooperative: wave stages 2 KB of K + 2 KB of V)
    ldsload16(kbase + (size_t)(g0 * 8 + srow) * HD + lcol * 8,           smem + g0 * 1024);
    ldsload16(kbase + (size_t)(g0 * 8 + 8 + srow) * HD + lcol * 8,       smem + g0 * 1024 + 1024);
    ldsload16(vbase + (size_t)(g0 * 8 + srow) * VSTR + lcol * 8,         smem + 16384 + g0 * 1024);
    ldsload16(vbase + (size_t)(g0 * 8 + 8 + srow) * VSTR + lcol * 8,     smem + 16384 + g0 * 1024 + 1024);

    for (int i = 0; i < 32; i++) {
        __syncthreads();   // tile-i loads drained (issued one full compute window ago)
        const int c0 = i * 64;
        const u16* Ks  = (const u16*)(smem + (i & 1) * 8192);
        const u16* Vts = (const u16*)(smem + 16384 + (i & 1) * 8192);
        if (i + 1 < 32) {
            const int cn = c0 + 64;
            char* nbK = smem + ((i + 1) & 1) * 8192;
            char* nbV = smem + 16384 + ((i + 1) & 1) * 8192;
            ldsload16(kbase + (size_t)(cn + g0 * 8 + srow) * HD + lcol * 8,       nbK + g0 * 1024);
            ldsload16(kbase + (size_t)(cn + g0 * 8 + 8 + srow) * HD + lcol * 8,   nbK + g0 * 1024 + 1024);
            ldsload16(vbase + (size_t)(g0 * 8 + srow) * VSTR + cn + lcol * 8,     nbV + g0 * 1024);
            ldsload16(vbase + (size_t)(g0 * 8 + 8 + srow) * VSTR + cn + lcol * 8, nbV + g0 * 1024 + 1024);
        }

        // per 16-kv chunk: S^T -> fixed-M softmax -> packed P (registers only)
        bf16x4 Pk[4][2];
#pragma unroll
        for (int ks = 0; ks < 4; ks++) {
            const int rb = (ks * 16 + l15) * 64;
            const bf16x8 ka0 = *(const bf16x8*)&Ks[rb + swk0];
            const bf16x8 ka1 = *(const bf16x8*)&Ks[rb + swk1];
            f32x4 St[2];
#pragma unroll
            for (int nt = 0; nt < 2; nt++) {
                f32x4 a = (f32x4)0.0f;
                a = mfma16(ka0, Qf[nt][0], a);
                a = mfma16(ka1, Qf[nt][1], a);
                St[nt] = a;
            }
            const f32x4 mv = *(const f32x4*)(m2b + c0 + ks * 16 + quad * 4);
#pragma unroll
            for (int nt = 0; nt < 2; nt++) {
                const float p0 = __builtin_amdgcn_exp2f(fmaf(St[nt][0], C2, mv[0]));
                const float p1 = __builtin_amdgcn_exp2f(fmaf(St[nt][1], C2, mv[1]));
                const float p2 = __builtin_amdgcn_exp2f(fmaf(St[nt][2], C2, mv[2]));
                const float p3 = __builtin_amdgcn_exp2f(fmaf(St[nt][3], C2, mv[3]));
                ls2[nt] += (p0 + p1) + (p2 + p3);
                union { unsigned int u[2]; bf16x4 v; } pk;
                pk.u[0] = pk_bf16(p0, p1);
                pk.u[1] = pk_bf16(p2, p3);
                Pk[ks][nt] = pk.v;
            }
        }

        // O^T[d][q] += V^T-frag * P-frag  (K=16 MFMA over kv chunks)
#pragma unroll
        for (int mt2 = 0; mt2 < 4; mt2++) {
            const u16* Vp = Vts + (mt2 * 16 + l15) * 64 + ((quad & 1) << 2);
            bf16x4 Va[4];
#pragma unroll
            for (int ks = 0; ks < 4; ks++)
                Va[ks] = *(const bf16x4*)(Vp +
                    ((((ks << 1) | (quad >> 1)) ^ (l15 & 7)) << 3));
#pragma unroll
            for (int nt = 0; nt < 2; nt++) {
                f32x4 acc = O[mt2][nt];
#pragma unroll
                for (int ks = 0; ks < 4; ks++)
                    acc = mfma16k16(Va[ks], Pk[ks][nt], acc);
                O[mt2][nt] = acc;
            }
        }
    }

    // l over quads (q col = nt*16+l15 lives in lanes {l15, +16, +32, +48})
#pragma unroll
    for (int nt = 0; nt < 2; nt++) {
        ls2[nt] += __shfl_xor(ls2[nt], 16);
        ls2[nt] += __shfl_xor(ls2[nt], 32);
    }
    const float linv0 = 1.0f / ls2[0];
    const float linv1 = 1.0f / ls2[1];

    // epilogue: transpose O^T -> [q][d] via wave-private LDS, coalesced store
    __syncthreads();   // protect K/V buffers from reuse while others still read
    float* Ot = (float*)smem + wave * (32 * 68);
#pragma unroll
    for (int mt2 = 0; mt2 < 4; mt2++)
#pragma unroll
        for (int nt = 0; nt < 2; nt++) {
            const f32x4 v = O[mt2][nt] * (nt ? linv1 : linv0);
            *(f32x4*)(Ot + (nt * 16 + l15) * 68 + mt2 * 16 + quad * 4) = v;
        }
    // wave-private region: intra-wave lgkm ordering suffices, no barrier
    {
        const int ql   = lane >> 1;          // 0..31
        const int half = lane & 1;           // 32-float half-row
        const float* srcp = Ot + ql * 68 + half * 32;
        u16* dstp = ctx + (size_t)(b * SEQ + q0 + wave * 32 + ql) * HID
                        + hh * 64 + half * 32;
#pragma unroll
        for (int j = 0; j < 4; j++) {
            union { u16 s[8]; uint4 v; } p;
#pragma unroll
            for (int ii = 0; ii < 8; ii++) p.s[ii] = f2bf(srcp[j * 8 + ii]);
            *(uint4*)(dstp + j * 8) = p.v;
        }
    }
}

// ---------------------------------------------------------------------------
extern "C" void kernel_launch(void* const* d_in, const int* in_sizes, int n_in,
                              void* d_out, int out_size, void* d_ws, size_t ws_size,
                              hipStream_t stream)
{
    const float* hs    = (const float*)d_in[0];
    const float* mask  = (const float*)d_in[1];
    const float* Wq    = (const float*)d_in[2];
    const float* bq    = (const float*)d_in[3];
    const float* Wk    = (const float*)d_in[4];
    const float* bk    = (const float*)d_in[5];
    const float* Wv    = (const float*)d_in[6];
    const float* bv    = (const float*)d_in[7];
    const float* Wd    = (const float*)d_in[8];
    const float* bd    = (const float*)d_in[9];
    const float* gamma = (const float*)d_in[10];
    const float* beta  = (const float*)d_in[11];
    float* out = (float*)d_out;

    const size_t NE = (size_t)MROWS * HID;
    u16* ws   = (u16*)d_ws;
    u16* h    = ws;                          // bf16 [MROWS][HID]
    u16* qbb  = ws + NE;                     // bf16 [B,NH,S,HD]
    u16* kbb  = qbb + NE;                    // bf16 [B,NH,S,HD]
    u16* vtb  = kbb + NE;                    // bf16 [HID][VSTR]
    u16* ctxb = vtb + (size_t)HID * VSTR;    // bf16 [MROWS][HID]
    u16* wqb  = ctxb + NE;
    u16* wkb  = wqb + HID * HID;
    u16* wvb  = wkb + HID * HID;
    u16* wdb  = wvb + HID * HID;
    float* m2 = (float*)(wdb + HID * HID);   // fp32 [MROWS] precomputed mask2

    prep_kernel<<<8196, 256, 0, stream>>>(hs, gamma, beta, h,
                                          Wq, Wk, Wv, Wd, wqb, wkb, wvb, wdb,
                                          mask, m2);

    qkv_gemm<<<768, 256, 0, stream>>>(h, wqb, wkb, wvb, bq, bk, bv, qbb, kbb, vtb);

    attn_mfma<<<512, 256, 0, stream>>>(qbb, kbb, vtb, m2, ctxb);

    out_gemm<<<256, 256, 0, stream>>>(ctxb, wdb, bd, out);
}